// Round 6
// baseline (87.516 us; speedup 1.0000x reference)
//
#include <hip/hip_runtime.h>
#include <math.h>
#include <stdint.h>

#define K_NN   16
#define BATCH  2
#define NA_    16384
#define NB_    8192
#define CH     128
// coords are [z,y,x]: z in [0,64), y in [0,256), x in [0,256); cell edge 16
#define CZ     4
#define CY     16
#define CX     16
#define NCELL  (CZ*CY*CX)   // 1024
#define CSH    4
#define PADKEY 0xFFF00000u  // > any real key ((134019<<14)|16383 = 0x82E0BFFF)

// ---------------- grid build kernels ----------------

__device__ __forceinline__ int cell_of(float p0, float p1, float p2) {
    const int cz = ((int)p0) >> CSH;
    const int cy = ((int)p1) >> CSH;
    const int cx = ((int)p2) >> CSH;
    return (cz * CY + cy) * CX + cx;
}

__global__ void count_kernel(const float* __restrict__ tpos, int* __restrict__ counts) {
    int i = blockIdx.x * 256 + threadIdx.x;
    if (i >= BATCH * NA_) return;
    int b = i / NA_;
    const float* tp = tpos + (size_t)i * 3;
    atomicAdd(&counts[b * NCELL + cell_of(tp[0], tp[1], tp[2])], 1);
}

__global__ void scan_kernel(const int* __restrict__ counts,
                            int2* __restrict__ meta, int* __restrict__ cursor) {
    __shared__ int wsum_[16];
    const int b = blockIdx.x, t = threadIdx.x, lane = t & 63, w = t >> 6;
    const int c = counts[b * NCELL + t];
    int x = c;
#pragma unroll
    for (int off = 1; off < 64; off <<= 1) {
        int u = __shfl_up(x, off);
        if (lane >= off) x += u;
    }
    if (lane == 63) wsum_[w] = x;
    __syncthreads();
    if (t < 16) {
        int v = wsum_[t];
#pragma unroll
        for (int off = 1; off < 16; off <<= 1) {
            int u = __shfl_up(v, off);
            if (t >= off) v += u;
        }
        wsum_[t] = v;
    }
    __syncthreads();
    const int incl = x + (w ? wsum_[w - 1] : 0);
    const int excl = incl - c;
    meta[b * NCELL + t]   = make_int2(excl, c);
    cursor[b * NCELL + t] = excl;
}

__global__ void scatter_kernel(const float* __restrict__ tpos,
                               int* __restrict__ cursor, float4* __restrict__ sorted) {
    int i = blockIdx.x * 256 + threadIdx.x;
    if (i >= BATCH * NA_) return;
    int b = i / NA_, p = i % NA_;
    const float* tp = tpos + (size_t)i * 3;
    float p0 = tp[0], p1 = tp[1], p2 = tp[2];
    int cell = cell_of(p0, p1, p2);
    int pos = atomicAdd(&cursor[b * NCELL + cell], 1);
    sorted[(size_t)b * NA_ + pos] = make_float4(p0, p1, p2, __int_as_float(p));
}

// ---------------- fallback merge: extract 16 smallest keys across the wave ----------------

template<int NS>
__device__ __forceinline__ void merge_extract(uint32_t (&k)[NS], uint32_t (&sel)[K_NN]) {
    uint32_t m = k[0];
#pragma unroll
    for (int j = 1; j < NS; ++j) m = min(m, k[j]);
#pragma unroll
    for (int r = 0; r < K_NN; ++r) {
        uint32_t v = m;
#pragma unroll
        for (int off = 32; off > 0; off >>= 1)
            v = min(v, (uint32_t)__shfl_xor((int)v, off));
        sel[r] = (uint32_t)__builtin_amdgcn_readfirstlane((int)v);
        if (m == v) {
#pragma unroll
            for (int j = 0; j < NS; ++j) k[j] = (k[j] == v) ? 0xFFFFFFFFu : k[j];
            m = k[0];
#pragma unroll
            for (int j = 1; j < NS; ++j) m = min(m, k[j]);
        }
    }
}

// ---------------- exact ring fallback (rare: corners / Poisson undershoot) ----------------

__device__ __noinline__ void ring_fallback(int lane, float s0, float s1, float s2,
                                           int scz, int scy, int scx, int rcov,
                                           const int2* __restrict__ mb,
                                           const float4* __restrict__ sb,
                                           uint32_t (&sel)[K_NN]) {
    for (int r = 1;; ++r) {
        uint32_t kl[K_NN];
#pragma unroll
        for (int j = 0; j < K_NN; ++j) kl[j] = PADKEY + 16 + j;
        if (r > 1) {
            uint32_t seed = 0xFFFFFFFFu;
#pragma unroll
            for (int j = 0; j < K_NN; ++j) if (lane == j) seed = sel[j];
            kl[0] = seed;
        }
        uint32_t curmax = kl[0];
#pragma unroll
        for (int j = 1; j < K_NN; ++j) curmax = max(curmax, kl[j]);

        for (int dz = -r; dz <= r; ++dz) {
            const int cz = scz + dz; if ((unsigned)cz >= CZ) continue;
            for (int dy = -r; dy <= r; ++dy) {
                const int cy = scy + dy; if ((unsigned)cy >= CY) continue;
                const int rowb = (cz * CY + cy) * CX;
                const bool fullrow = (r == 1) || (max(abs(dz), abs(dy)) == r);
                int xl[2], xh[2];
                if (fullrow) {
                    xl[0] = max(scx - r, 0); xh[0] = min(scx + r, CX - 1);
                    xl[1] = 1; xh[1] = 0;
                } else {
                    xl[0] = scx - r; xh[0] = scx - r;
                    xl[1] = scx + r; xh[1] = scx + r;
                    if (xl[0] < 0)      { xl[0] = 1; xh[0] = 0; }
                    if (xh[1] > CX - 1) { xl[1] = 1; xh[1] = 0; }
                }
#pragma unroll
                for (int q = 0; q < 2; ++q) {
                    if (xl[q] > xh[q]) continue;
                    const int2 mlo = mb[rowb + xl[q]];
                    const int2 mhi = mb[rowb + xh[q]];
                    const int st = mlo.x, ln = mhi.x + mhi.y - st;
                    for (int o = 0; o < ln; o += 64) {
                        const int j2 = o + lane;
                        const bool act = j2 < ln;
                        const int a = st + (act ? j2 : 0);
                        const float4 p = sb[a];
                        const float d0 = s0 - p.x, d1 = s1 - p.y, d2c = s2 - p.z;
                        const float d2 = d0 * d0 + d1 * d1 + d2c * d2c;
                        uint32_t kv = ((uint32_t)d2 << 14) | (uint32_t)__float_as_int(p.w);
                        kv = act ? kv : 0xFFFFFFFFu;
                        if (kv < curmax) {
#pragma unroll
                            for (int j = 0; j < K_NN; ++j)
                                kl[j] = (kl[j] == curmax) ? kv : kl[j];
                            curmax = kl[0];
#pragma unroll
                            for (int j = 1; j < K_NN; ++j) curmax = max(curmax, kl[j]);
                        }
                    }
                }
            }
        }
        merge_extract<K_NN>(kl, sel);
        const uint32_t d16 = sel[K_NN - 1] >> 14;
        if (d16 <= (uint32_t)(256 * r * r) || r >= rcov) break;
    }
}

// ---------------- helpers for the fast path ----------------

__device__ __forceinline__ int compact_keys(int lane, const uint32_t (&key)[12],
                                            uint32_t keyT, uint32_t* dst) {
    int nsel = 0;
#pragma unroll
    for (int j = 0; j < 12; ++j) {
        const bool pred = key[j] < keyT;
        const unsigned long long m = __ballot(pred);
        const int offp = __builtin_amdgcn_mbcnt_hi(
            (uint32_t)(m >> 32), __builtin_amdgcn_mbcnt_lo((uint32_t)m, 0));
        if (pred && (nsel + offp) < 132) dst[nsel + offp] = key[j];
        nsel += (int)__builtin_popcountll(m);
    }
    return nsel;
}

__device__ __forceinline__ void rank_write(int lane, const uint32_t* keys, int nsel,
                                           uint32_t* selLds) {
    const uint32_t myk0 = (lane      < nsel) ? keys[lane]      : 0xFFFFFFFFu;
    const uint32_t myk1 = (64 + lane < nsel) ? keys[64 + lane] : 0xFFFFFFFFu;
    uint32_t r0 = 0, r1 = 0;
    const int nmax4 = (nsel + 3) & ~3;
    for (int j = 0; j < nmax4; j += 4) {
        const uint4 k4 = *(const uint4*)&keys[j];
        r0 += (k4.x < myk0) + (k4.y < myk0) + (k4.z < myk0) + (k4.w < myk0);
        r1 += (k4.x < myk1) + (k4.y < myk1) + (k4.z < myk1) + (k4.w < myk1);
    }
    if (r0 < K_NN) selLds[r0] = myk0;
    if (r1 < K_NN) selLds[r1] = myk1;
}

// ---------------- main KNN + aggregation: 2 students per wave ----------------

__global__ __launch_bounds__(256) void knn_cells_kernel(
    const float* __restrict__ tfeat,   // [B, NA, C]
    const float* __restrict__ spos,    // [B, NB, 3]
    const int2*  __restrict__ meta,    // [B, NCELL] (start, count)
    const float4* __restrict__ sorted, // [B, NA] (z,y,x,idx-bits)
    float* __restrict__ out)           // [B, NB, C]
{
    __shared__ uint32_t sKeys[8][132];
    __shared__ uint32_t sSel[8][16];

    const int tid  = threadIdx.x;
    const int lane = tid & 63;
    const int wave = tid >> 6;

    const int bpb = NB_ / 8;                       // 1024 blocks per batch
    const int b = blockIdx.x / bpb;
    const int n0 = (blockIdx.x % bpb) * 8 + wave * 2;   // students n0, n0+1

    const int2*   mb = meta   + (size_t)b * NCELL;
    const float4* sb = sorted + (size_t)b * NA_;

    // ---- phase 1: positions (interleaved) ----
    float s0[2], s1[2], s2[2];
    int scz[2], scy[2], scx[2], rcov[2];
#pragma unroll
    for (int s = 0; s < 2; ++s) {
        const float* sp = spos + ((size_t)b * NB_ + n0 + s) * 3;
        s0[s] = sp[0]; s1[s] = sp[1]; s2[s] = sp[2];
    }
#pragma unroll
    for (int s = 0; s < 2; ++s) {
        scz[s] = __builtin_amdgcn_readfirstlane(((int)s0[s]) >> CSH);
        scy[s] = __builtin_amdgcn_readfirstlane(((int)s1[s]) >> CSH);
        scx[s] = __builtin_amdgcn_readfirstlane(((int)s2[s]) >> CSH);
        int rc = max(max(scx[s], CX - 1 - scx[s]), max(scy[s], CY - 1 - scy[s]));
        rcov[s] = max(rc, max(scz[s], CZ - 1 - scz[s]));
    }

    // ---- phase 2: 9 row-ranges per student (wave-uniform) ----
    int rstart[2][9], rlen[2][9];
    int nov[2] = {0, 0};
    bool fast[2] = {true, true};
#pragma unroll
    for (int kk = 0; kk < 9; ++kk) {
#pragma unroll
        for (int s = 0; s < 2; ++s) {
            const int cz = scz[s] + kk / 3 - 1, cy = scy[s] + kk % 3 - 1;
            int st = 0, ln = 0;
            if ((unsigned)cz < CZ && (unsigned)cy < CY) {
                const int rowb = (cz * CY + cy) * CX;
                const int cxlo = max(scx[s] - 1, 0), cxhi = min(scx[s] + 1, CX - 1);
                const int2 mlo = mb[rowb + cxlo];
                const int2 mhi = mb[rowb + cxhi];
                st = mlo.x; ln = mhi.x + mhi.y - mlo.x;
            }
            rstart[s][kk] = st; rlen[s][kk] = ln;
            if (ln > 64) ++nov[s];
            if (ln > 128) fast[s] = false;
        }
    }
#pragma unroll
    for (int s = 0; s < 2; ++s) if (nov[s] > 3) fast[s] = false;

    // ---- phase 3: branchless slotted scan (interleaved loads) ----
    uint32_t key[2][12];
#pragma unroll
    for (int kk = 0; kk < 9; ++kk) {
#pragma unroll
        for (int s = 0; s < 2; ++s) {
            const int ln = rlen[s][kk];
            const bool act = lane < ln;
            const int a = rstart[s][kk] + (act ? lane : 0);
            const float4 p = sb[a];
            const float d0 = s0[s] - p.x, d1 = s1[s] - p.y, d2c = s2[s] - p.z;
            const float d2 = d0 * d0 + d1 * d1 + d2c * d2c;
            const uint32_t kv = ((uint32_t)d2 << 14) | (uint32_t)__float_as_int(p.w);
            key[s][kk] = act ? kv : (PADKEY + kk);
        }
    }
#pragma unroll
    for (int s = 0; s < 2; ++s) {
        key[s][9] = PADKEY + 9; key[s][10] = PADKEY + 10; key[s][11] = PADKEY + 11;
        if (nov[s] && fast[s]) {
            int oc = 9;
#pragma unroll
            for (int kk = 0; kk < 9; ++kk) {
                if (rlen[s][kk] > 64) {
                    const int j2 = 64 + lane;
                    const bool act = j2 < rlen[s][kk];
                    const int a = rstart[s][kk] + (act ? j2 : 0);
                    const float4 p = sb[a];
                    const float d0 = s0[s] - p.x, d1 = s1[s] - p.y, d2c = s2[s] - p.z;
                    const float d2 = d0 * d0 + d1 * d1 + d2c * d2c;
                    const uint32_t kv = ((uint32_t)d2 << 14) | (uint32_t)__float_as_int(p.w);
                    if (oc == 9)       key[s][9]  = act ? kv : key[s][9];
                    else if (oc == 10) key[s][10] = act ? kv : key[s][10];
                    else               key[s][11] = act ? kv : key[s][11];
                    ++oc;
                }
            }
        }
    }

    // ---- phase 4: two-tier census (interleaved shuffle chains) ----
    const uint32_t KT1 = 169u << 14;
    const uint32_t KT2 = 288u << 14;
    uint32_t pc[2] = {0, 0};
#pragma unroll
    for (int j = 0; j < 12; ++j) {
#pragma unroll
        for (int s = 0; s < 2; ++s) {
            pc[s] += (key[s][j] < KT1) ? 1u : 0u;
            pc[s] += (key[s][j] < KT2) ? 0x10000u : 0u;
        }
    }
#pragma unroll
    for (int off = 32; off > 0; off >>= 1) {
#pragma unroll
        for (int s = 0; s < 2; ++s)
            pc[s] += (uint32_t)__shfl_xor((int)pc[s], off);
    }
    uint32_t keyT[2];
#pragma unroll
    for (int s = 0; s < 2; ++s) {
        const uint32_t c1 = (uint32_t)__builtin_amdgcn_readfirstlane((int)(pc[s] & 0xFFFFu));
        const uint32_t c2 = (uint32_t)__builtin_amdgcn_readfirstlane((int)(pc[s] >> 16));
        keyT[s] = 0;
        if (fast[s]) {
            if (c1 >= K_NN) keyT[s] = KT1;
            else if (c2 >= K_NN) keyT[s] = KT2;
        }
    }

    // ---- phase 5: compact -> rank -> broadcast (wave-private LDS) ----
    uint32_t sel[2][K_NN];
    bool done[2] = {false, false};
    int nsel[2] = {0, 0};
    bool ok[2] = {false, false};
#pragma unroll
    for (int s = 0; s < 2; ++s) {
        if (keyT[s]) {
            nsel[s] = compact_keys(lane, key[s], keyT[s], &sKeys[wave * 2 + s][0]);
            ok[s] = (nsel[s] >= K_NN && nsel[s] <= 128);
            if (ok[s]) {
                const int padn = (4 - (nsel[s] & 3)) & 3;
                if (lane < padn) sKeys[wave * 2 + s][nsel[s] + lane] = 0xFFFFFFFFu;
            }
        }
    }
    __threadfence_block();
#pragma unroll
    for (int s = 0; s < 2; ++s)
        if (ok[s]) rank_write(lane, &sKeys[wave * 2 + s][0], nsel[s], &sSel[wave * 2 + s][0]);
    __threadfence_block();
#pragma unroll
    for (int s = 0; s < 2; ++s) {
        if (ok[s]) {
            const uint4 sA = *(const uint4*)&sSel[wave * 2 + s][0];
            const uint4 sB = *(const uint4*)&sSel[wave * 2 + s][4];
            const uint4 sC = *(const uint4*)&sSel[wave * 2 + s][8];
            const uint4 sD = *(const uint4*)&sSel[wave * 2 + s][12];
            sel[s][0]  = (uint32_t)__builtin_amdgcn_readfirstlane((int)sA.x);
            sel[s][1]  = (uint32_t)__builtin_amdgcn_readfirstlane((int)sA.y);
            sel[s][2]  = (uint32_t)__builtin_amdgcn_readfirstlane((int)sA.z);
            sel[s][3]  = (uint32_t)__builtin_amdgcn_readfirstlane((int)sA.w);
            sel[s][4]  = (uint32_t)__builtin_amdgcn_readfirstlane((int)sB.x);
            sel[s][5]  = (uint32_t)__builtin_amdgcn_readfirstlane((int)sB.y);
            sel[s][6]  = (uint32_t)__builtin_amdgcn_readfirstlane((int)sB.z);
            sel[s][7]  = (uint32_t)__builtin_amdgcn_readfirstlane((int)sB.w);
            sel[s][8]  = (uint32_t)__builtin_amdgcn_readfirstlane((int)sC.x);
            sel[s][9]  = (uint32_t)__builtin_amdgcn_readfirstlane((int)sC.y);
            sel[s][10] = (uint32_t)__builtin_amdgcn_readfirstlane((int)sC.z);
            sel[s][11] = (uint32_t)__builtin_amdgcn_readfirstlane((int)sC.w);
            sel[s][12] = (uint32_t)__builtin_amdgcn_readfirstlane((int)sD.x);
            sel[s][13] = (uint32_t)__builtin_amdgcn_readfirstlane((int)sD.y);
            sel[s][14] = (uint32_t)__builtin_amdgcn_readfirstlane((int)sD.z);
            sel[s][15] = (uint32_t)__builtin_amdgcn_readfirstlane((int)sD.w);
            done[s] = true;
        }
    }

    // ---- phase 6: exact ring fallback (rare) ----
    if (!done[0]) ring_fallback(lane, s0[0], s1[0], s2[0], scz[0], scy[0], scx[0],
                                rcov[0], mb, sb, sel[0]);
    if (!done[1]) ring_fallback(lane, s0[1], s1[1], s2[1], scz[1], scy[1], scx[1],
                                rcov[1], mb, sb, sel[1]);

    // ---- phase 7: weights + gather (float2 per lane, interleaved) ----
    float wsum[2] = {0.f, 0.f};
#pragma unroll
    for (int j = 0; j < K_NN; ++j) {
#pragma unroll
        for (int s = 0; s < 2; ++s)
            wsum[s] += __expf(-0.5f * (float)(sel[s][j] >> 14));
    }
    const float inv0 = 1.0f / wsum[0];
    const float inv1 = 1.0f / wsum[1];

    const float* fb = tfeat + (size_t)b * NA_ * CH;
    float2 acc0 = make_float2(0.f, 0.f);
    float2 acc1 = make_float2(0.f, 0.f);
#pragma unroll
    for (int j = 0; j < K_NN; ++j) {
        const int iA = (int)(sel[0][j] & 16383u);
        const int iB = (int)(sel[1][j] & 16383u);
        const float2 vA = ((const float2*)(fb + (size_t)iA * CH))[lane];
        const float2 vB = ((const float2*)(fb + (size_t)iB * CH))[lane];
        const float wA = __expf(-0.5f * (float)(sel[0][j] >> 14)) * inv0;
        const float wB = __expf(-0.5f * (float)(sel[1][j] >> 14)) * inv1;
        acc0.x += wA * vA.x; acc0.y += wA * vA.y;
        acc1.x += wB * vB.x; acc1.y += wB * vB.y;
    }

    float2* o0 = (float2*)(out + ((size_t)b * NB_ + n0) * CH);
    float2* o1 = (float2*)(out + ((size_t)b * NB_ + n0 + 1) * CH);
    o0[lane] = acc0;
    o1[lane] = acc1;
}

// ---------------- launch ----------------

extern "C" void kernel_launch(void* const* d_in, const int* in_sizes, int n_in,
                              void* d_out, int out_size, void* d_ws, size_t ws_size,
                              hipStream_t stream) {
    const float* tfeat = (const float*)d_in[0];   // [B,NA,C]
    const float* tpos  = (const float*)d_in[1];   // [B,NA,3]
    const float* spos  = (const float*)d_in[2];   // [B,NB,3]
    float* out = (float*)d_out;                   // [B,NB,C]

    const size_t OFF_COUNTS = 0;
    const size_t OFF_META   = 8192;
    const size_t OFF_CURSOR = 24576;
    const size_t OFF_SORTED = 32768;

    char* ws = (char*)d_ws;
    int*    counts = (int*)(ws + OFF_COUNTS);
    int2*   meta   = (int2*)(ws + OFF_META);
    int*    cursor = (int*)(ws + OFF_CURSOR);
    float4* sorted = (float4*)(ws + OFF_SORTED);

    hipMemsetAsync(counts, 0, BATCH * NCELL * sizeof(int), stream);
    count_kernel<<<(BATCH * NA_ + 255) / 256, 256, 0, stream>>>(tpos, counts);
    scan_kernel<<<BATCH, NCELL, 0, stream>>>(counts, meta, cursor);
    scatter_kernel<<<(BATCH * NA_ + 255) / 256, 256, 0, stream>>>(tpos, cursor, sorted);
    knn_cells_kernel<<<BATCH * (NB_ / 8), 256, 0, stream>>>(tfeat, spos, meta, sorted, out);
}

// Round 7
// 70.392 us; speedup vs baseline: 1.2433x; 1.2433x over previous
//
#include <hip/hip_runtime.h>
#include <math.h>
#include <stdint.h>

#define K_NN   16
#define BATCH  2
#define NA_    16384
#define NB_    8192
#define CH     128
// coords are [z,y,x]: z in [0,64), y in [0,256), x in [0,256); cell edge 16
#define CZ     4
#define CY     16
#define CX     16
#define NCELL  (CZ*CY*CX)   // 1024
#define CSH    4
#define PADKEY 0xFFF00000u  // > any real key ((134019<<14)|16383 = 0x82E0BFFF)

// ---------------- grid build kernels ----------------

__device__ __forceinline__ int cell_of(float p0, float p1, float p2) {
    const int cz = ((int)p0) >> CSH;
    const int cy = ((int)p1) >> CSH;
    const int cx = ((int)p2) >> CSH;
    return (cz * CY + cy) * CX + cx;
}

__global__ void count_kernel(const float* __restrict__ tpos, int* __restrict__ counts) {
    int i = blockIdx.x * 256 + threadIdx.x;
    if (i >= BATCH * NA_) return;
    int b = i / NA_;
    const float* tp = tpos + (size_t)i * 3;
    atomicAdd(&counts[b * NCELL + cell_of(tp[0], tp[1], tp[2])], 1);
}

__global__ void scan_kernel(const int* __restrict__ counts,
                            int2* __restrict__ meta, int* __restrict__ cursor) {
    __shared__ int wsum_[16];
    const int b = blockIdx.x, t = threadIdx.x, lane = t & 63, w = t >> 6;
    const int c = counts[b * NCELL + t];
    int x = c;
#pragma unroll
    for (int off = 1; off < 64; off <<= 1) {
        int u = __shfl_up(x, off);
        if (lane >= off) x += u;
    }
    if (lane == 63) wsum_[w] = x;
    __syncthreads();
    if (t < 16) {
        int v = wsum_[t];
#pragma unroll
        for (int off = 1; off < 16; off <<= 1) {
            int u = __shfl_up(v, off);
            if (t >= off) v += u;
        }
        wsum_[t] = v;
    }
    __syncthreads();
    const int incl = x + (w ? wsum_[w - 1] : 0);
    const int excl = incl - c;
    meta[b * NCELL + t]   = make_int2(excl, c);
    cursor[b * NCELL + t] = excl;
}

__global__ void scatter_kernel(const float* __restrict__ tpos,
                               int* __restrict__ cursor, float4* __restrict__ sorted) {
    int i = blockIdx.x * 256 + threadIdx.x;
    if (i >= BATCH * NA_) return;
    int b = i / NA_, p = i % NA_;
    const float* tp = tpos + (size_t)i * 3;
    float p0 = tp[0], p1 = tp[1], p2 = tp[2];
    int cell = cell_of(p0, p1, p2);
    int pos = atomicAdd(&cursor[b * NCELL + cell], 1);
    sorted[(size_t)b * NA_ + pos] = make_float4(p0, p1, p2, __int_as_float(p));
}

// ---------------- exact ring fallback (rare; results -> wave-private LDS) ----------------
// All locals statically indexed (registers only). Winners stored to selLds by lane 0.

__device__ __noinline__ void ring_fallback(int lane, float s0, float s1, float s2,
                                           int scz, int scy, int scx, int rcov,
                                           const int2* __restrict__ mb,
                                           const float4* __restrict__ sb,
                                           uint32_t* selLds) {
    uint32_t sel[K_NN];
#pragma unroll
    for (int j = 0; j < K_NN; ++j) sel[j] = 0xFFFFFFFFu;

    for (int r = 1;; ++r) {
        uint32_t kl[K_NN];
#pragma unroll
        for (int j = 0; j < K_NN; ++j) kl[j] = PADKEY + 16 + j;
        if (r > 1) {
            uint32_t seed = 0xFFFFFFFFu;
#pragma unroll
            for (int j = 0; j < K_NN; ++j) if (lane == j) seed = sel[j];
            kl[0] = seed;
        }
        uint32_t curmax = kl[0];
#pragma unroll
        for (int j = 1; j < K_NN; ++j) curmax = max(curmax, kl[j]);

        for (int dz = -r; dz <= r; ++dz) {
            const int cz = scz + dz; if ((unsigned)cz >= CZ) continue;
            for (int dy = -r; dy <= r; ++dy) {
                const int cy = scy + dy; if ((unsigned)cy >= CY) continue;
                const int rowb = (cz * CY + cy) * CX;
                const bool fullrow = (r == 1) || (max(abs(dz), abs(dy)) == r);
                int xl[2], xh[2];
                if (fullrow) {
                    xl[0] = max(scx - r, 0); xh[0] = min(scx + r, CX - 1);
                    xl[1] = 1; xh[1] = 0;
                } else {
                    xl[0] = scx - r; xh[0] = scx - r;
                    xl[1] = scx + r; xh[1] = scx + r;
                    if (xl[0] < 0)      { xl[0] = 1; xh[0] = 0; }
                    if (xh[1] > CX - 1) { xl[1] = 1; xh[1] = 0; }
                }
#pragma unroll
                for (int q = 0; q < 2; ++q) {
                    if (xl[q] > xh[q]) continue;
                    const int2 mlo = mb[rowb + xl[q]];
                    const int2 mhi = mb[rowb + xh[q]];
                    const int st = mlo.x, ln = mhi.x + mhi.y - st;
                    for (int o = 0; o < ln; o += 64) {
                        const int j2 = o + lane;
                        const bool act = j2 < ln;
                        const int a = st + (act ? j2 : 0);
                        const float4 p = sb[a];
                        const float d0 = s0 - p.x, d1 = s1 - p.y, d2c = s2 - p.z;
                        const float d2 = d0 * d0 + d1 * d1 + d2c * d2c;
                        uint32_t kv = ((uint32_t)d2 << 14) | (uint32_t)__float_as_int(p.w);
                        kv = act ? kv : 0xFFFFFFFFu;
                        if (kv < curmax) {
#pragma unroll
                            for (int j = 0; j < K_NN; ++j)
                                kl[j] = (kl[j] == curmax) ? kv : kl[j];
                            curmax = kl[0];
#pragma unroll
                            for (int j = 1; j < K_NN; ++j) curmax = max(curmax, kl[j]);
                        }
                    }
                }
            }
        }

        // merge: extract 16 smallest across wave (wave-uniform into sel[])
        uint32_t m = kl[0];
#pragma unroll
        for (int j = 1; j < K_NN; ++j) m = min(m, kl[j]);
#pragma unroll
        for (int rr = 0; rr < K_NN; ++rr) {
            uint32_t v = m;
#pragma unroll
            for (int off = 32; off > 0; off >>= 1)
                v = min(v, (uint32_t)__shfl_xor((int)v, off));
            sel[rr] = (uint32_t)__builtin_amdgcn_readfirstlane((int)v);
            if (m == v) {
#pragma unroll
                for (int j = 0; j < K_NN; ++j) kl[j] = (kl[j] == v) ? 0xFFFFFFFFu : kl[j];
                m = kl[0];
#pragma unroll
                for (int j = 1; j < K_NN; ++j) m = min(m, kl[j]);
            }
        }

        const uint32_t d16 = sel[K_NN - 1] >> 14;
        if (d16 <= (uint32_t)(256 * r * r) || r >= rcov) break;
    }

    if (lane == 0) {
#pragma unroll
        for (int j = 0; j < K_NN; ++j) selLds[j] = sel[j];
    }
}

// ---------------- helpers for the fast path ----------------

__device__ __forceinline__ int compact_keys(int lane, const uint32_t (&key)[12],
                                            uint32_t keyT, uint32_t* dst) {
    int nsel = 0;
#pragma unroll
    for (int j = 0; j < 12; ++j) {
        const bool pred = key[j] < keyT;
        const unsigned long long m = __ballot(pred);
        const int offp = __builtin_amdgcn_mbcnt_hi(
            (uint32_t)(m >> 32), __builtin_amdgcn_mbcnt_lo((uint32_t)m, 0));
        if (pred && (nsel + offp) < 132) dst[nsel + offp] = key[j];
        nsel += (int)__builtin_popcountll(m);
    }
    return nsel;
}

__device__ __forceinline__ void rank_write(int lane, const uint32_t* keys, int nsel,
                                           uint32_t* selLds) {
    const uint32_t myk0 = (lane      < nsel) ? keys[lane]      : 0xFFFFFFFFu;
    const uint32_t myk1 = (64 + lane < nsel) ? keys[64 + lane] : 0xFFFFFFFFu;
    uint32_t r0 = 0, r1 = 0;
    const int nmax4 = (nsel + 3) & ~3;
    for (int j = 0; j < nmax4; j += 4) {
        const uint4 k4 = *(const uint4*)&keys[j];
        r0 += (k4.x < myk0) + (k4.y < myk0) + (k4.z < myk0) + (k4.w < myk0);
        r1 += (k4.x < myk1) + (k4.y < myk1) + (k4.z < myk1) + (k4.w < myk1);
    }
    if (r0 < K_NN) selLds[r0] = myk0;
    if (r1 < K_NN) selLds[r1] = myk1;
}

// ---------------- main KNN + aggregation: 2 students per wave ----------------

__global__ __launch_bounds__(256) void knn_cells_kernel(
    const float* __restrict__ tfeat,   // [B, NA, C]
    const float* __restrict__ spos,    // [B, NB, 3]
    const int2*  __restrict__ meta,    // [B, NCELL] (start, count)
    const float4* __restrict__ sorted, // [B, NA] (z,y,x,idx-bits)
    float* __restrict__ out)           // [B, NB, C]
{
    __shared__ uint32_t sKeys[8][132];
    __shared__ uint32_t sSel[8][16];

    const int tid  = threadIdx.x;
    const int lane = tid & 63;
    const int wave = tid >> 6;

    const int bpb = NB_ / 8;                       // 1024 blocks per batch
    const int b = blockIdx.x / bpb;
    const int n0 = (blockIdx.x % bpb) * 8 + wave * 2;   // students n0, n0+1

    const int2*   mb = meta   + (size_t)b * NCELL;
    const float4* sb = sorted + (size_t)b * NA_;

    // ---- phase 1: positions (interleaved) ----
    float s0[2], s1[2], s2[2];
    int scz[2], scy[2], scx[2], rcov[2];
#pragma unroll
    for (int s = 0; s < 2; ++s) {
        const float* sp = spos + ((size_t)b * NB_ + n0 + s) * 3;
        s0[s] = sp[0]; s1[s] = sp[1]; s2[s] = sp[2];
    }
#pragma unroll
    for (int s = 0; s < 2; ++s) {
        scz[s] = __builtin_amdgcn_readfirstlane(((int)s0[s]) >> CSH);
        scy[s] = __builtin_amdgcn_readfirstlane(((int)s1[s]) >> CSH);
        scx[s] = __builtin_amdgcn_readfirstlane(((int)s2[s]) >> CSH);
        int rc = max(max(scx[s], CX - 1 - scx[s]), max(scy[s], CY - 1 - scy[s]));
        rcov[s] = max(rc, max(scz[s], CZ - 1 - scz[s]));
    }

    // ---- phase 2: 9 row-ranges per student (wave-uniform) ----
    int rstart[2][9], rlen[2][9];
    int nov[2] = {0, 0};
    bool fast[2] = {true, true};
#pragma unroll
    for (int kk = 0; kk < 9; ++kk) {
#pragma unroll
        for (int s = 0; s < 2; ++s) {
            const int cz = scz[s] + kk / 3 - 1, cy = scy[s] + kk % 3 - 1;
            int st = 0, ln = 0;
            if ((unsigned)cz < CZ && (unsigned)cy < CY) {
                const int rowb = (cz * CY + cy) * CX;
                const int cxlo = max(scx[s] - 1, 0), cxhi = min(scx[s] + 1, CX - 1);
                const int2 mlo = mb[rowb + cxlo];
                const int2 mhi = mb[rowb + cxhi];
                st = mlo.x; ln = mhi.x + mhi.y - mlo.x;
            }
            rstart[s][kk] = st; rlen[s][kk] = ln;
            if (ln > 64) ++nov[s];
            if (ln > 128) fast[s] = false;
        }
    }
#pragma unroll
    for (int s = 0; s < 2; ++s) if (nov[s] > 3) fast[s] = false;

    // ---- phase 3: branchless slotted scan (interleaved loads) ----
    uint32_t key[2][12];
#pragma unroll
    for (int kk = 0; kk < 9; ++kk) {
#pragma unroll
        for (int s = 0; s < 2; ++s) {
            const int ln = rlen[s][kk];
            const bool act = lane < ln;
            const int a = rstart[s][kk] + (act ? lane : 0);
            const float4 p = sb[a];
            const float d0 = s0[s] - p.x, d1 = s1[s] - p.y, d2c = s2[s] - p.z;
            const float d2 = d0 * d0 + d1 * d1 + d2c * d2c;
            const uint32_t kv = ((uint32_t)d2 << 14) | (uint32_t)__float_as_int(p.w);
            key[s][kk] = act ? kv : (PADKEY + kk);
        }
    }
#pragma unroll
    for (int s = 0; s < 2; ++s) {
        key[s][9] = PADKEY + 9; key[s][10] = PADKEY + 10; key[s][11] = PADKEY + 11;
        if (nov[s] && fast[s]) {
            int oc = 9;
#pragma unroll
            for (int kk = 0; kk < 9; ++kk) {
                if (rlen[s][kk] > 64) {
                    const int j2 = 64 + lane;
                    const bool act = j2 < rlen[s][kk];
                    const int a = rstart[s][kk] + (act ? j2 : 0);
                    const float4 p = sb[a];
                    const float d0 = s0[s] - p.x, d1 = s1[s] - p.y, d2c = s2[s] - p.z;
                    const float d2 = d0 * d0 + d1 * d1 + d2c * d2c;
                    const uint32_t kv = ((uint32_t)d2 << 14) | (uint32_t)__float_as_int(p.w);
                    if (oc == 9)       key[s][9]  = act ? kv : key[s][9];
                    else if (oc == 10) key[s][10] = act ? kv : key[s][10];
                    else               key[s][11] = act ? kv : key[s][11];
                    ++oc;
                }
            }
        }
    }

    // ---- phase 4: two-tier census (interleaved shuffle chains) ----
    const uint32_t KT1 = 169u << 14;
    const uint32_t KT2 = 288u << 14;   // ring-1 stop bound: outside box >= 289
    uint32_t pc[2] = {0, 0};
#pragma unroll
    for (int j = 0; j < 12; ++j) {
#pragma unroll
        for (int s = 0; s < 2; ++s) {
            pc[s] += (key[s][j] < KT1) ? 1u : 0u;
            pc[s] += (key[s][j] < KT2) ? 0x10000u : 0u;
        }
    }
#pragma unroll
    for (int off = 32; off > 0; off >>= 1) {
#pragma unroll
        for (int s = 0; s < 2; ++s)
            pc[s] += (uint32_t)__shfl_xor((int)pc[s], off);
    }
    uint32_t keyT[2];
#pragma unroll
    for (int s = 0; s < 2; ++s) {
        const uint32_t c1 = (uint32_t)__builtin_amdgcn_readfirstlane((int)(pc[s] & 0xFFFFu));
        const uint32_t c2 = (uint32_t)__builtin_amdgcn_readfirstlane((int)(pc[s] >> 16));
        keyT[s] = 0;
        if (fast[s]) {
            if (c1 >= K_NN) keyT[s] = KT1;
            else if (c2 >= K_NN) keyT[s] = KT2;
        }
    }

    // ---- phase 5: compact -> rank -> winners in wave-private LDS ----
    int nsel[2] = {0, 0};
    bool ok[2] = {false, false};
#pragma unroll
    for (int s = 0; s < 2; ++s) {
        if (keyT[s]) {
            nsel[s] = compact_keys(lane, key[s], keyT[s], &sKeys[wave * 2 + s][0]);
            ok[s] = (nsel[s] >= K_NN && nsel[s] <= 128);
            if (ok[s]) {
                const int padn = (4 - (nsel[s] & 3)) & 3;
                if (lane < padn) sKeys[wave * 2 + s][nsel[s] + lane] = 0xFFFFFFFFu;
            }
        }
    }
    __threadfence_block();
#pragma unroll
    for (int s = 0; s < 2; ++s)
        if (ok[s]) rank_write(lane, &sKeys[wave * 2 + s][0], nsel[s], &sSel[wave * 2 + s][0]);

    // ---- phase 6: exact ring fallback (rare; writes same LDS slot) ----
    if (!ok[0]) ring_fallback(lane, s0[0], s1[0], s2[0], scz[0], scy[0], scx[0],
                              rcov[0], mb, sb, &sSel[wave * 2 + 0][0]);
    if (!ok[1]) ring_fallback(lane, s0[1], s1[1], s2[1], scz[1], scy[1], scx[1],
                              rcov[1], mb, sb, &sSel[wave * 2 + 1][0]);
    __threadfence_block();

    // ---- unified broadcast from LDS -> wave-uniform sel registers ----
    uint32_t sel[2][K_NN];
#pragma unroll
    for (int s = 0; s < 2; ++s) {
        const uint4 sA = *(const uint4*)&sSel[wave * 2 + s][0];
        const uint4 sB = *(const uint4*)&sSel[wave * 2 + s][4];
        const uint4 sC = *(const uint4*)&sSel[wave * 2 + s][8];
        const uint4 sD = *(const uint4*)&sSel[wave * 2 + s][12];
        sel[s][0]  = (uint32_t)__builtin_amdgcn_readfirstlane((int)sA.x);
        sel[s][1]  = (uint32_t)__builtin_amdgcn_readfirstlane((int)sA.y);
        sel[s][2]  = (uint32_t)__builtin_amdgcn_readfirstlane((int)sA.z);
        sel[s][3]  = (uint32_t)__builtin_amdgcn_readfirstlane((int)sA.w);
        sel[s][4]  = (uint32_t)__builtin_amdgcn_readfirstlane((int)sB.x);
        sel[s][5]  = (uint32_t)__builtin_amdgcn_readfirstlane((int)sB.y);
        sel[s][6]  = (uint32_t)__builtin_amdgcn_readfirstlane((int)sB.z);
        sel[s][7]  = (uint32_t)__builtin_amdgcn_readfirstlane((int)sB.w);
        sel[s][8]  = (uint32_t)__builtin_amdgcn_readfirstlane((int)sC.x);
        sel[s][9]  = (uint32_t)__builtin_amdgcn_readfirstlane((int)sC.y);
        sel[s][10] = (uint32_t)__builtin_amdgcn_readfirstlane((int)sC.z);
        sel[s][11] = (uint32_t)__builtin_amdgcn_readfirstlane((int)sC.w);
        sel[s][12] = (uint32_t)__builtin_amdgcn_readfirstlane((int)sD.x);
        sel[s][13] = (uint32_t)__builtin_amdgcn_readfirstlane((int)sD.y);
        sel[s][14] = (uint32_t)__builtin_amdgcn_readfirstlane((int)sD.z);
        sel[s][15] = (uint32_t)__builtin_amdgcn_readfirstlane((int)sD.w);
    }

    // ---- phase 7: weights + gather (float2 per lane, interleaved) ----
    float wsum[2] = {0.f, 0.f};
#pragma unroll
    for (int j = 0; j < K_NN; ++j) {
#pragma unroll
        for (int s = 0; s < 2; ++s)
            wsum[s] += __expf(-0.5f * (float)(sel[s][j] >> 14));
    }
    const float inv0 = 1.0f / wsum[0];
    const float inv1 = 1.0f / wsum[1];

    const float* fb = tfeat + (size_t)b * NA_ * CH;
    float2 acc0 = make_float2(0.f, 0.f);
    float2 acc1 = make_float2(0.f, 0.f);
#pragma unroll
    for (int j = 0; j < K_NN; ++j) {
        const int iA = (int)(sel[0][j] & 16383u);
        const int iB = (int)(sel[1][j] & 16383u);
        const float2 vA = ((const float2*)(fb + (size_t)iA * CH))[lane];
        const float2 vB = ((const float2*)(fb + (size_t)iB * CH))[lane];
        const float wA = __expf(-0.5f * (float)(sel[0][j] >> 14)) * inv0;
        const float wB = __expf(-0.5f * (float)(sel[1][j] >> 14)) * inv1;
        acc0.x += wA * vA.x; acc0.y += wA * vA.y;
        acc1.x += wB * vB.x; acc1.y += wB * vB.y;
    }

    float2* o0 = (float2*)(out + ((size_t)b * NB_ + n0) * CH);
    float2* o1 = (float2*)(out + ((size_t)b * NB_ + n0 + 1) * CH);
    o0[lane] = acc0;
    o1[lane] = acc1;
}

// ---------------- launch ----------------

extern "C" void kernel_launch(void* const* d_in, const int* in_sizes, int n_in,
                              void* d_out, int out_size, void* d_ws, size_t ws_size,
                              hipStream_t stream) {
    const float* tfeat = (const float*)d_in[0];   // [B,NA,C]
    const float* tpos  = (const float*)d_in[1];   // [B,NA,3]
    const float* spos  = (const float*)d_in[2];   // [B,NB,3]
    float* out = (float*)d_out;                   // [B,NB,C]

    const size_t OFF_COUNTS = 0;
    const size_t OFF_META   = 8192;
    const size_t OFF_CURSOR = 24576;
    const size_t OFF_SORTED = 32768;

    char* ws = (char*)d_ws;
    int*    counts = (int*)(ws + OFF_COUNTS);
    int2*   meta   = (int2*)(ws + OFF_META);
    int*    cursor = (int*)(ws + OFF_CURSOR);
    float4* sorted = (float4*)(ws + OFF_SORTED);

    hipMemsetAsync(counts, 0, BATCH * NCELL * sizeof(int), stream);
    count_kernel<<<(BATCH * NA_ + 255) / 256, 256, 0, stream>>>(tpos, counts);
    scan_kernel<<<BATCH, NCELL, 0, stream>>>(counts, meta, cursor);
    scatter_kernel<<<(BATCH * NA_ + 255) / 256, 256, 0, stream>>>(tpos, cursor, sorted);
    knn_cells_kernel<<<BATCH * (NB_ / 8), 256, 0, stream>>>(tfeat, spos, meta, sorted, out);
}

// Round 8
// 64.581 us; speedup vs baseline: 1.3551x; 1.0900x over previous
//
#include <hip/hip_runtime.h>
#include <math.h>
#include <stdint.h>

#define K_NN   16
#define BATCH  2
#define NA_    16384
#define NB_    8192
#define CH     128
// coords are [z,y,x]: z in [0,64), y in [0,256), x in [0,256); cell edge 16
#define CZ     4
#define CY     16
#define CX     16
#define NCELL  (CZ*CY*CX)   // 1024
#define CSH    4
#define PADKEY 0xFFF00000u  // > any real key ((134019<<14)|16383 = 0x82E0BFFF)

__device__ __forceinline__ int cell_of(float p0, float p1, float p2) {
    const int cz = ((int)p0) >> CSH;
    const int cy = ((int)p1) >> CSH;
    const int cx = ((int)p2) >> CSH;
    return (cz * CY + cy) * CX + cx;
}

// ---------------- fused grid build: histogram + scan + scatter, 1 block/batch ----------------

__global__ __launch_bounds__(1024) void build_kernel(const float* __restrict__ tpos,
                                                     int2* __restrict__ meta,
                                                     float4* __restrict__ sorted) {
    __shared__ int cnt[NCELL];      // histogram, then cursor
    __shared__ int wpart[16];

    const int b = blockIdx.x, t = threadIdx.x, lane = t & 63, w = t >> 6;
    cnt[t] = 0;
    __syncthreads();

    const float* tb = tpos + (size_t)b * NA_ * 3;
    float p0v[16], p1v[16], p2v[16];
    int cells[16];
#pragma unroll
    for (int i = 0; i < 16; ++i) {
        const float* p = tb + (size_t)(t + i * 1024) * 3;
        p0v[i] = p[0]; p1v[i] = p[1]; p2v[i] = p[2];
        cells[i] = cell_of(p0v[i], p1v[i], p2v[i]);
        atomicAdd(&cnt[cells[i]], 1);
    }
    __syncthreads();

    // block-wide exclusive scan over 1024 cells
    const int c = cnt[t];
    int x = c;
#pragma unroll
    for (int off = 1; off < 64; off <<= 1) {
        int u = __shfl_up(x, off);
        if (lane >= off) x += u;
    }
    if (lane == 63) wpart[w] = x;
    __syncthreads();
    if (t < 16) {
        int v = wpart[t];
#pragma unroll
        for (int off = 1; off < 16; off <<= 1) {
            int u = __shfl_up(v, off);
            if (t >= off) v += u;
        }
        wpart[t] = v;
    }
    __syncthreads();
    const int excl = x - c + (w ? wpart[w - 1] : 0);
    meta[b * NCELL + t] = make_int2(excl, c);
    __syncthreads();
    cnt[t] = excl;                  // reuse as cursor
    __syncthreads();

#pragma unroll
    for (int i = 0; i < 16; ++i) {
        const int pos = atomicAdd(&cnt[cells[i]], 1);
        sorted[(size_t)b * NA_ + pos] =
            make_float4(p0v[i], p1v[i], p2v[i], __int_as_float(t + i * 1024));
    }
}

// ---------------- exact ring fallback (rare; results -> wave-private LDS) ----------------

__device__ __noinline__ void ring_fallback(int lane, float s0, float s1, float s2,
                                           int scz, int scy, int scx, int rcov,
                                           const int2* __restrict__ mb,
                                           const float4* __restrict__ sb,
                                           uint32_t* selLds) {
    uint32_t sel[K_NN];
#pragma unroll
    for (int j = 0; j < K_NN; ++j) sel[j] = 0xFFFFFFFFu;

    for (int r = 1;; ++r) {
        uint32_t kl[K_NN];
#pragma unroll
        for (int j = 0; j < K_NN; ++j) kl[j] = PADKEY + 16 + j;
        if (r > 1) {
            uint32_t seed = 0xFFFFFFFFu;
#pragma unroll
            for (int j = 0; j < K_NN; ++j) if (lane == j) seed = sel[j];
            kl[0] = seed;
        }
        uint32_t curmax = kl[0];
#pragma unroll
        for (int j = 1; j < K_NN; ++j) curmax = max(curmax, kl[j]);

        for (int dz = -r; dz <= r; ++dz) {
            const int cz = scz + dz; if ((unsigned)cz >= CZ) continue;
            for (int dy = -r; dy <= r; ++dy) {
                const int cy = scy + dy; if ((unsigned)cy >= CY) continue;
                const int rowb = (cz * CY + cy) * CX;
                const bool fullrow = (r == 1) || (max(abs(dz), abs(dy)) == r);
                int xl[2], xh[2];
                if (fullrow) {
                    xl[0] = max(scx - r, 0); xh[0] = min(scx + r, CX - 1);
                    xl[1] = 1; xh[1] = 0;
                } else {
                    xl[0] = scx - r; xh[0] = scx - r;
                    xl[1] = scx + r; xh[1] = scx + r;
                    if (xl[0] < 0)      { xl[0] = 1; xh[0] = 0; }
                    if (xh[1] > CX - 1) { xl[1] = 1; xh[1] = 0; }
                }
#pragma unroll
                for (int q = 0; q < 2; ++q) {
                    if (xl[q] > xh[q]) continue;
                    const int2 mlo = mb[rowb + xl[q]];
                    const int2 mhi = mb[rowb + xh[q]];
                    const int st = mlo.x, ln = mhi.x + mhi.y - st;
                    for (int o = 0; o < ln; o += 64) {
                        const int j2 = o + lane;
                        const bool act = j2 < ln;
                        const int a = st + (act ? j2 : 0);
                        const float4 p = sb[a];
                        const float d0 = s0 - p.x, d1 = s1 - p.y, d2c = s2 - p.z;
                        const float d2 = d0 * d0 + d1 * d1 + d2c * d2c;
                        uint32_t kv = ((uint32_t)d2 << 14) | (uint32_t)__float_as_int(p.w);
                        kv = act ? kv : 0xFFFFFFFFu;
                        if (kv < curmax) {
#pragma unroll
                            for (int j = 0; j < K_NN; ++j)
                                kl[j] = (kl[j] == curmax) ? kv : kl[j];
                            curmax = kl[0];
#pragma unroll
                            for (int j = 1; j < K_NN; ++j) curmax = max(curmax, kl[j]);
                        }
                    }
                }
            }
        }

        uint32_t m = kl[0];
#pragma unroll
        for (int j = 1; j < K_NN; ++j) m = min(m, kl[j]);
#pragma unroll
        for (int rr = 0; rr < K_NN; ++rr) {
            uint32_t v = m;
#pragma unroll
            for (int off = 32; off > 0; off >>= 1)
                v = min(v, (uint32_t)__shfl_xor((int)v, off));
            sel[rr] = (uint32_t)__builtin_amdgcn_readfirstlane((int)v);
            if (m == v) {
#pragma unroll
                for (int j = 0; j < K_NN; ++j) kl[j] = (kl[j] == v) ? 0xFFFFFFFFu : kl[j];
                m = kl[0];
#pragma unroll
                for (int j = 1; j < K_NN; ++j) m = min(m, kl[j]);
            }
        }

        const uint32_t d16 = sel[K_NN - 1] >> 14;
        if (d16 <= (uint32_t)(256 * r * r) || r >= rcov) break;
    }

    if (lane == 0) {
#pragma unroll
        for (int j = 0; j < K_NN; ++j) selLds[j] = sel[j];
    }
}

// ---------------- fast-path helpers ----------------

__device__ __forceinline__ int compact_keys(int lane, const uint32_t (&key)[12],
                                            uint32_t keyT, uint32_t* dst) {
    int nsel = 0;
#pragma unroll
    for (int j = 0; j < 12; ++j) {
        const bool pred = key[j] < keyT;
        const unsigned long long m = __ballot(pred);
        const int offp = __builtin_amdgcn_mbcnt_hi(
            (uint32_t)(m >> 32), __builtin_amdgcn_mbcnt_lo((uint32_t)m, 0));
        if (pred && (nsel + offp) < 132) dst[nsel + offp] = key[j];
        nsel += (int)__builtin_popcountll(m);
    }
    return nsel;
}

__device__ __forceinline__ void rank_write(int lane, const uint32_t* keys, int nsel,
                                           uint32_t* selLds) {
    const uint32_t myk0 = (lane      < nsel) ? keys[lane]      : 0xFFFFFFFFu;
    const uint32_t myk1 = (64 + lane < nsel) ? keys[64 + lane] : 0xFFFFFFFFu;
    uint32_t r0 = 0, r1 = 0;
    const int nmax4 = (nsel + 3) & ~3;
    for (int j = 0; j < nmax4; j += 4) {
        const uint4 k4 = *(const uint4*)&keys[j];
        r0 += (k4.x < myk0) + (k4.y < myk0) + (k4.z < myk0) + (k4.w < myk0);
        r1 += (k4.x < myk1) + (k4.y < myk1) + (k4.z < myk1) + (k4.w < myk1);
    }
    if (r0 < K_NN) selLds[r0] = myk0;
    if (r1 < K_NN) selLds[r1] = myk1;
}

// ---------------- main KNN + aggregation: 1 student per wave, 2 waves/block ----------------

__global__ __launch_bounds__(128) void knn_cells_kernel(
    const float* __restrict__ tfeat,   // [B, NA, C]
    const float* __restrict__ spos,    // [B, NB, 3]
    const int2*  __restrict__ meta,    // [B, NCELL] (start, count)
    const float4* __restrict__ sorted, // [B, NA] (z,y,x,idx-bits)
    float* __restrict__ out)           // [B, NB, C]
{
    __shared__ uint32_t sKeys[2][132];
    __shared__ uint32_t sSel[2][16];

    const int tid  = threadIdx.x;
    const int lane = tid & 63;
    const int wave = tid >> 6;

    const int bpb = NB_ / 2;                    // 4096 blocks per batch
    const int b = blockIdx.x / bpb;
    const int n = (blockIdx.x % bpb) * 2 + wave;

    const int2*   mb = meta   + (size_t)b * NCELL;
    const float4* sb = sorted + (size_t)b * NA_;

    // ---- positions ----
    const float* sp = spos + ((size_t)b * NB_ + n) * 3;
    const float s0 = sp[0], s1 = sp[1], s2 = sp[2];   // z, y, x
    const int scz = __builtin_amdgcn_readfirstlane(((int)s0) >> CSH);
    const int scy = __builtin_amdgcn_readfirstlane(((int)s1) >> CSH);
    const int scx = __builtin_amdgcn_readfirstlane(((int)s2) >> CSH);
    int rcov = max(max(scx, CX - 1 - scx), max(scy, CY - 1 - scy));
    rcov = max(rcov, max(scz, CZ - 1 - scz));

    // ---- 9 row-ranges (wave-uniform) ----
    int rstart[9], rlen[9];
    const int cxlo = max(scx - 1, 0), cxhi = min(scx + 1, CX - 1);
    int nov = 0; bool fast = true;
#pragma unroll
    for (int kk = 0; kk < 9; ++kk) {
        const int cz = scz + kk / 3 - 1, cy = scy + kk % 3 - 1;
        int st = 0, ln = 0;
        if ((unsigned)cz < CZ && (unsigned)cy < CY) {
            const int rowb = (cz * CY + cy) * CX;
            const int2 mlo = mb[rowb + cxlo];
            const int2 mhi = mb[rowb + cxhi];
            st = mlo.x; ln = mhi.x + mhi.y - mlo.x;
        }
        rstart[kk] = st; rlen[kk] = ln;
        if (ln > 64) ++nov;
        if (ln > 128) fast = false;
    }
    if (nov > 3) fast = false;

    // ---- branchless slotted scan ----
    uint32_t key[12];
#pragma unroll
    for (int kk = 0; kk < 9; ++kk) {
        const int ln = rlen[kk];
        const bool act = lane < ln;
        const int a = rstart[kk] + (act ? lane : 0);
        const float4 p = sb[a];
        const float d0 = s0 - p.x, d1 = s1 - p.y, d2c = s2 - p.z;
        const float d2 = d0 * d0 + d1 * d1 + d2c * d2c;
        const uint32_t kv = ((uint32_t)d2 << 14) | (uint32_t)__float_as_int(p.w);
        key[kk] = act ? kv : (PADKEY + kk);
    }
    key[9] = PADKEY + 9; key[10] = PADKEY + 10; key[11] = PADKEY + 11;
    if (nov && fast) {
        int oc = 9;
#pragma unroll
        for (int kk = 0; kk < 9; ++kk) {
            if (rlen[kk] > 64) {
                const int j2 = 64 + lane;
                const bool act = j2 < rlen[kk];
                const int a = rstart[kk] + (act ? j2 : 0);
                const float4 p = sb[a];
                const float d0 = s0 - p.x, d1 = s1 - p.y, d2c = s2 - p.z;
                const float d2 = d0 * d0 + d1 * d1 + d2c * d2c;
                const uint32_t kv = ((uint32_t)d2 << 14) | (uint32_t)__float_as_int(p.w);
                if (oc == 9)       key[9]  = act ? kv : key[9];
                else if (oc == 10) key[10] = act ? kv : key[10];
                else               key[11] = act ? kv : key[11];
                ++oc;
            }
        }
    }

    // ---- two-tier census ----
    const uint32_t KT1 = 169u << 14;
    const uint32_t KT2 = 288u << 14;   // ring-1 stop bound: unexamined >= 289
    uint32_t pc = 0;
#pragma unroll
    for (int j = 0; j < 12; ++j) {
        pc += (key[j] < KT1) ? 1u : 0u;
        pc += (key[j] < KT2) ? 0x10000u : 0u;
    }
#pragma unroll
    for (int off = 32; off > 0; off >>= 1)
        pc += (uint32_t)__shfl_xor((int)pc, off);
    const uint32_t c1 = (uint32_t)__builtin_amdgcn_readfirstlane((int)(pc & 0xFFFFu));
    const uint32_t c2 = (uint32_t)__builtin_amdgcn_readfirstlane((int)(pc >> 16));
    uint32_t keyT = 0;
    if (fast) {
        if (c1 >= K_NN) keyT = KT1;
        else if (c2 >= K_NN) keyT = KT2;
    }

    // ---- compact -> rank -> winners in wave-private LDS ----
    bool ok = false;
    if (keyT) {
        const int nsel = compact_keys(lane, key, keyT, &sKeys[wave][0]);
        ok = (nsel >= K_NN && nsel <= 128);
        if (ok) {
            const int padn = (4 - (nsel & 3)) & 3;
            if (lane < padn) sKeys[wave][nsel + lane] = 0xFFFFFFFFu;
            __threadfence_block();
            rank_write(lane, &sKeys[wave][0], nsel, &sSel[wave][0]);
        }
    }
    if (!ok)
        ring_fallback(lane, s0, s1, s2, scz, scy, scx, rcov, mb, sb, &sSel[wave][0]);
    __threadfence_block();

    // ---- broadcast winners -> wave-uniform registers ----
    const uint4 sA = *(const uint4*)&sSel[wave][0];
    const uint4 sB = *(const uint4*)&sSel[wave][4];
    const uint4 sC = *(const uint4*)&sSel[wave][8];
    const uint4 sD = *(const uint4*)&sSel[wave][12];
    uint32_t sel[K_NN];
    sel[0]  = (uint32_t)__builtin_amdgcn_readfirstlane((int)sA.x);
    sel[1]  = (uint32_t)__builtin_amdgcn_readfirstlane((int)sA.y);
    sel[2]  = (uint32_t)__builtin_amdgcn_readfirstlane((int)sA.z);
    sel[3]  = (uint32_t)__builtin_amdgcn_readfirstlane((int)sA.w);
    sel[4]  = (uint32_t)__builtin_amdgcn_readfirstlane((int)sB.x);
    sel[5]  = (uint32_t)__builtin_amdgcn_readfirstlane((int)sB.y);
    sel[6]  = (uint32_t)__builtin_amdgcn_readfirstlane((int)sB.z);
    sel[7]  = (uint32_t)__builtin_amdgcn_readfirstlane((int)sB.w);
    sel[8]  = (uint32_t)__builtin_amdgcn_readfirstlane((int)sC.x);
    sel[9]  = (uint32_t)__builtin_amdgcn_readfirstlane((int)sC.y);
    sel[10] = (uint32_t)__builtin_amdgcn_readfirstlane((int)sC.z);
    sel[11] = (uint32_t)__builtin_amdgcn_readfirstlane((int)sC.w);
    sel[12] = (uint32_t)__builtin_amdgcn_readfirstlane((int)sD.x);
    sel[13] = (uint32_t)__builtin_amdgcn_readfirstlane((int)sD.y);
    sel[14] = (uint32_t)__builtin_amdgcn_readfirstlane((int)sD.z);
    sel[15] = (uint32_t)__builtin_amdgcn_readfirstlane((int)sD.w);

    // ---- weights + gather (float2 per lane) ----
    float w[K_NN];
    float wsum = 0.f;
#pragma unroll
    for (int j = 0; j < K_NN; ++j) {
        w[j] = __expf(-0.5f * (float)(sel[j] >> 14));
        wsum += w[j];
    }
    const float inv = 1.0f / wsum;

    const float* fb = tfeat + (size_t)b * NA_ * CH;
    float2 acc = make_float2(0.f, 0.f);
#pragma unroll
    for (int j = 0; j < K_NN; ++j) {
        const int idx = (int)(sel[j] & 16383u);
        const float2 v = ((const float2*)(fb + (size_t)idx * CH))[lane];
        const float ww = w[j] * inv;
        acc.x += ww * v.x; acc.y += ww * v.y;
    }

    float2* o = (float2*)(out + ((size_t)b * NB_ + n) * CH);
    o[lane] = acc;
}

// ---------------- launch ----------------

extern "C" void kernel_launch(void* const* d_in, const int* in_sizes, int n_in,
                              void* d_out, int out_size, void* d_ws, size_t ws_size,
                              hipStream_t stream) {
    const float* tfeat = (const float*)d_in[0];   // [B,NA,C]
    const float* tpos  = (const float*)d_in[1];   // [B,NA,3]
    const float* spos  = (const float*)d_in[2];   // [B,NB,3]
    float* out = (float*)d_out;                   // [B,NB,C]

    char* ws = (char*)d_ws;
    int2*   meta   = (int2*)(ws);                 // 2*1024*8B = 16 KiB
    float4* sorted = (float4*)(ws + 16384);       // 2*16384*16B = 512 KiB

    build_kernel<<<BATCH, 1024, 0, stream>>>(tpos, meta, sorted);
    knn_cells_kernel<<<BATCH * (NB_ / 2), 128, 0, stream>>>(tfeat, spos, meta, sorted, out);
}